// Round 13
// baseline (216.107 us; speedup 1.0000x reference)
//
#include <hip/hip_runtime.h>
#include <hip/hip_fp16.h>

#define NN 100000
#define NE 2500000
#define RANGE 128
#define RSHIFT 7
#define RMASK 127
#define NBUCK 782                       // ceil(NN/128)
#define CAP 4096                        // fixed bucket capacity (mean 3197, sd ~56)
#define CHUNK 16384
#define NBLK_A ((NE + CHUNK - 1) / CHUNK)   // 153
#define BCAP 4096                       // passB LDS stage cap

__device__ __forceinline__ float relu_(float x){ return fmaxf(x, 0.f); }

// ---- single-pass partition: per-block LDS histogram -> atomic bucket
//      reservation -> write packed keys (col<<7)|(row&127) into fixed-cap buckets
__global__ __launch_bounds__(512) void k_partition1(
    const int* __restrict__ row, const int* __restrict__ col,
    int* __restrict__ cursor, unsigned int* __restrict__ keys)
{
  __shared__ int hist[NBUCK];
  __shared__ int base[NBUCK];
  int t = threadIdx.x, b = blockIdx.x;
  for (int i = t; i < NBUCK; i += 512) hist[i] = 0;
  __syncthreads();
  int e0 = b * CHUNK + t;
#pragma unroll
  for (int k = 0; k < CHUNK / 512; ++k) {
    int e = e0 + k * 512;
    if (e < NE) atomicAdd(&hist[row[e] >> RSHIFT], 1);
  }
  __syncthreads();
  for (int i = t; i < NBUCK; i += 512) {
    int c = hist[i];
    base[i] = c ? (i * CAP + atomicAdd(&cursor[i], c)) : 0;
    hist[i] = 0;
  }
  __syncthreads();
#pragma unroll
  for (int k = 0; k < CHUNK / 512; ++k) {
    int e = e0 + k * 512;
    if (e < NE) {
      int r = row[e];
      int bi = r >> RSHIFT;
      int idx = atomicAdd(&hist[bi], 1);
      keys[base[bi] + idx] = ((unsigned)col[e] << RSHIFT) | (unsigned)(r & RMASK);
    }
  }
}

// per-bucket: LDS-staged keys -> hist -> scan -> rowseg + ecol placement,
// then FUSED layer-1 agg (nf recompute) + layer-1 update GEMM -> h16b direct.
__global__ __launch_bounds__(512) void k_passB_l1(
    const int* __restrict__ cursor, const unsigned int* __restrict__ keys,
    const float* __restrict__ nf, const float* __restrict__ Win,
    const float* __restrict__ bin, const float* __restrict__ W,
    const float* __restrict__ bupd,
    int* __restrict__ ecol, int2* __restrict__ rowseg,
    __half* __restrict__ h16b)
{
  __shared__ unsigned keysl[BCAP];
  __shared__ int hist[RANGE];
  __shared__ int sc[RANGE];
  __shared__ int segs[RANGE];
  __shared__ int sege[RANGE];
  __shared__ float Ws[2048];
  __shared__ float bs[32];
  int t = threadIdx.x, b = blockIdx.x;
  for (int i = t; i < 2048; i += 512) Ws[i] = W[i];
  if (t < 32) bs[t] = bupd[t];
  int s0 = b * CAP;
  int cnt = cursor[b];
  if (t < RANGE) hist[t] = 0;
  __syncthreads();
  for (int i = t; i < cnt; i += 512) {
    unsigned k = keys[s0 + i];
    if (i < BCAP) keysl[i] = k;
    atomicAdd(&hist[k & RMASK], 1);
  }
  __syncthreads();
  int my = (t < RANGE) ? hist[t] : 0;
  if (t < RANGE) sc[t] = my;
  __syncthreads();
  for (int off = 1; off < RANGE; off <<= 1) {
    int v = 0;
    if (t < RANGE && t >= off) v = sc[t - off];
    __syncthreads();
    if (t < RANGE) sc[t] += v;
    __syncthreads();
  }
  if (t < RANGE) {
    int ex = sc[t] - my;
    int n = b * RANGE + t;
    if (n < NN) rowseg[n] = make_int2(s0 + ex, s0 + sc[t]);
    segs[t] = ex;
    sege[t] = sc[t];
    hist[t] = ex;                 // placement cursor
  }
  __syncthreads();
  for (int i = t; i < cnt; i += 512) {
    unsigned key = (i < BCAP) ? keysl[i] : keys[s0 + i];
    int rl = (int)(key & RMASK);
    int idx = atomicAdd(&hist[rl], 1);
    ecol[s0 + idx] = (int)(key >> RSHIFT);
  }
  __syncthreads();   // ecol visible block-wide; segments in segs/sege

  const float2* nf2 = (const float2*)nf;
  for (int slot = t; slot < RANGE * 4; slot += 512) {
    int node = slot >> 2, q = slot & 3;
    int n = b * RANGE + node;
    if (n >= NN) continue;       // whole 4-lane group shares n
    float w0[8], w1[8], bb[8];
#pragma unroll
    for (int j = 0; j < 8; ++j) {
      w0[j] = Win[q * 8 + j];
      w1[j] = Win[32 + q * 8 + j];
      bb[j] = bin[q * 8 + j];
    }
    int ss = segs[node], ee = sege[node];
    float acc[8];
#pragma unroll
    for (int j = 0; j < 8; ++j) acc[j] = 0.f;
    int i = ss;
    for (; i + 2 <= ee; i += 2) {
      int c0 = ecol[s0 + i], c1 = ecol[s0 + i + 1];   // L2-hot
      float2 f0 = nf2[c0];
      float2 f1 = nf2[c1];
#pragma unroll
      for (int j = 0; j < 8; ++j) {
        acc[j] += relu_(fmaf(f0.x, w0[j], fmaf(f0.y, w1[j], bb[j])));
        acc[j] += relu_(fmaf(f1.x, w0[j], fmaf(f1.y, w1[j], bb[j])));
      }
    }
    if (i < ee) {
      float2 f = nf2[ecol[s0 + i]];
#pragma unroll
      for (int j = 0; j < 8; ++j)
        acc[j] += relu_(fmaf(f.x, w0[j], fmaf(f.y, w1[j], bb[j])));
    }
    float dinv = 1.0f / fmaxf((float)(ee - ss), 1.0f);
    float g[8], a[8];
    float2 fn = nf2[n];
#pragma unroll
    for (int j = 0; j < 8; ++j) {
      g[j] = acc[j] * dinv;
      a[j] = relu_(fmaf(fn.x, w0[j], fmaf(fn.y, w1[j], bb[j])));
    }
    // 64x32 GEMM slice via 4-lane shfl exchange
    float o[8];
#pragma unroll
    for (int j = 0; j < 8; ++j) o[j] = bs[q * 8 + j];
#pragma unroll
    for (int src = 0; src < 4; ++src) {
#pragma unroll
      for (int k = 0; k < 8; ++k) {
        float xh = __shfl(a[k], src, 4);
        float xg = __shfl(g[k], src, 4);
        const float* wr1 = Ws + (src * 8 + k) * 32 + q * 8;
        const float* wr2 = Ws + (32 + src * 8 + k) * 32 + q * 8;
#pragma unroll
        for (int j = 0; j < 8; ++j) {
          o[j] = fmaf(xh, wr1[j], o[j]);
          o[j] = fmaf(xg, wr2[j], o[j]);
        }
      }
    }
    uint4 pk;
    __half2* pp = (__half2*)&pk;
#pragma unroll
    for (int k = 0; k < 4; ++k)
      pp[k] = __floats2half2_rn(relu_(o[2*k]), relu_(o[2*k+1]));
    ((uint4*)h16b)[(size_t)n * 4 + q] = pk;
  }
}

// ---- fused layer-2, register-exchange version (full occupancy):
// agg = mean gather(h16b[ecol]); h2 = relu([h16b,agg]@W+b);
// u = h2@We1[0:32]+be1 ; v = h2@We1[32:64]   (64 nodes x 4 lanes / block)
__global__ __launch_bounds__(256) void k_agg_update2_uv(
    const int2* __restrict__ rowseg, const int* __restrict__ ecol,
    const __half* __restrict__ h16in, const float* __restrict__ W,
    const float* __restrict__ b, const float* __restrict__ We1,
    const float* __restrict__ be1, __half* __restrict__ u,
    __half* __restrict__ v)
{
  __shared__ float Ws[2048];
  __shared__ float Es[2048];
  __shared__ float bs[32];
  __shared__ float bes[32];
  int t = threadIdx.x;
  for (int i = t; i < 2048; i += 256) { Ws[i] = W[i]; Es[i] = We1[i]; }
  if (t < 32) { bs[t] = b[t]; bes[t] = be1[t]; }
  __syncthreads();
  int q = t & 3, ln = t >> 2;
  int n = blockIdx.x * 64 + ln;
  if (n >= NN) return;          // group-uniform exit; shfl stays intra-group
  const uint4* hv = (const uint4*)h16in;

  int2 seg = rowseg[n];
  float acc[8];
#pragma unroll
  for (int j = 0; j < 8; ++j) acc[j] = 0.f;
  int i = seg.x;
  for (; i + 2 <= seg.y; i += 2) {
    int c0 = ecol[i], c1 = ecol[i + 1];
    uint4 x0 = hv[c0 * 4 + q];
    uint4 x1 = hv[c1 * 4 + q];
    const __half2* p0 = (const __half2*)&x0;
    const __half2* p1 = (const __half2*)&x1;
#pragma unroll
    for (int k = 0; k < 4; ++k) {
      float2 f0 = __half22float2(p0[k]);
      float2 f1 = __half22float2(p1[k]);
      acc[2*k]   += f0.x + f1.x;
      acc[2*k+1] += f0.y + f1.y;
    }
  }
  if (i < seg.y) {
    uint4 x = hv[ecol[i] * 4 + q];
    const __half2* hp = (const __half2*)&x;
#pragma unroll
    for (int k = 0; k < 4; ++k) {
      float2 f = __half22float2(hp[k]);
      acc[2*k] += f.x; acc[2*k+1] += f.y;
    }
  }
  float dinv = 1.0f / fmaxf((float)(seg.y - seg.x), 1.0f);
  float a[8], g[8];
  {
    uint4 hx = hv[n * 4 + q];
    const __half2* hp = (const __half2*)&hx;
#pragma unroll
    for (int k = 0; k < 4; ++k) {
      float2 f = __half22float2(hp[k]);
      a[2*k] = f.x; a[2*k+1] = f.y;
      g[2*k] = acc[2*k] * dinv; g[2*k+1] = acc[2*k+1] * dinv;
    }
  }
  // GEMM1: h2 = relu([a|g] @ W + b), 4-lane shfl exchange
  float h2[8];
#pragma unroll
  for (int j = 0; j < 8; ++j) h2[j] = bs[q*8 + j];
#pragma unroll
  for (int src = 0; src < 4; ++src) {
#pragma unroll
    for (int k = 0; k < 8; ++k) {
      float xh = __shfl(a[k], src, 4);
      float xg = __shfl(g[k], src, 4);
      const float* wr1 = Ws + (src * 8 + k) * 32 + q * 8;
      const float* wr2 = Ws + (32 + src * 8 + k) * 32 + q * 8;
#pragma unroll
      for (int j = 0; j < 8; ++j) {
        h2[j] = fmaf(xh, wr1[j], h2[j]);
        h2[j] = fmaf(xg, wr2[j], h2[j]);
      }
    }
  }
#pragma unroll
  for (int j = 0; j < 8; ++j) h2[j] = relu_(h2[j]);
  // GEMM2: u = h2@Es[0:32]+be1 ; v = h2@Es[32:64]
  float au[8], av[8];
#pragma unroll
  for (int j = 0; j < 8; ++j) { au[j] = bes[q*8 + j]; av[j] = 0.f; }
#pragma unroll
  for (int src = 0; src < 4; ++src) {
#pragma unroll
    for (int k = 0; k < 8; ++k) {
      float xk = __shfl(h2[k], src, 4);
      const float* wu = Es + (src * 8 + k) * 32 + q * 8;
      const float* wv = Es + (32 + src * 8 + k) * 32 + q * 8;
#pragma unroll
      for (int j = 0; j < 8; ++j) {
        au[j] = fmaf(xk, wu[j], au[j]);
        av[j] = fmaf(xk, wv[j], av[j]);
      }
    }
  }
  uint4 pu, pv;
  __half2* up = (__half2*)&pu;
  __half2* vp = (__half2*)&pv;
#pragma unroll
  for (int k = 0; k < 4; ++k) {
    up[k] = __floats2half2_rn(au[2*k], au[2*k+1]);
    vp[k] = __floats2half2_rn(av[2*k], av[2*k+1]);
  }
  ((uint4*)u)[n * 4 + q] = pu;
  ((uint4*)v)[n * 4 + q] = pv;
}

// flux[e] = relu(u[row]+v[col]).We2 + be2   (4 lanes/edge, uint4 fp16 loads)
__global__ __launch_bounds__(256) void k_flux(
    const int* __restrict__ row, const int* __restrict__ col,
    const __half* __restrict__ u, const __half* __restrict__ v,
    const float* __restrict__ We2, const float* __restrict__ be2,
    float* __restrict__ out)
{
  int gid = blockIdx.x * 256 + threadIdx.x;
  int e = gid >> 2, q = gid & 3;
  if (e >= NE) return;
  int r = row[e], c = col[e];
  uint4 ua = ((const uint4*)u)[r * 4 + q];   // 8 halfs
  uint4 vb = ((const uint4*)v)[c * 4 + q];
  const __half2* ah = (const __half2*)&ua;
  const __half2* bh = (const __half2*)&vb;
  const float4* w4 = (const float4*)(We2 + q * 8);
  float4 w0 = w4[0], w1 = w4[1];
  float p = 0.f;
  {
    float2 a = __half22float2(ah[0]), b = __half22float2(bh[0]);
    p += relu_(a.x + b.x) * w0.x + relu_(a.y + b.y) * w0.y;
    a = __half22float2(ah[1]); b = __half22float2(bh[1]);
    p += relu_(a.x + b.x) * w0.z + relu_(a.y + b.y) * w0.w;
    a = __half22float2(ah[2]); b = __half22float2(bh[2]);
    p += relu_(a.x + b.x) * w1.x + relu_(a.y + b.y) * w1.y;
    a = __half22float2(ah[3]); b = __half22float2(bh[3]);
    p += relu_(a.x + b.x) * w1.z + relu_(a.y + b.y) * w1.w;
  }
  p += __shfl_xor(p, 1, 4);
  p += __shfl_xor(p, 2, 4);
  if (q == 0) out[e] = p + be2[0];
}

extern "C" void kernel_launch(void* const* d_in, const int* in_sizes, int n_in,
                              void* d_out, int out_size, void* d_ws, size_t ws_size,
                              hipStream_t stream) {
  const float* nf   = (const float*)d_in[0];
  const int*   ei   = (const int*)d_in[1];
  const float* Win  = (const float*)d_in[2];
  const float* bin  = (const float*)d_in[3];
  const float* Wupd = (const float*)d_in[4];
  const float* bupd = (const float*)d_in[5];
  const float* We1  = (const float*)d_in[6];
  const float* be1  = (const float*)d_in[7];
  const float* We2  = (const float*)d_in[8];
  const float* be2  = (const float*)d_in[9];
  float* out = (float*)d_out;

  const int* row = ei;
  const int* col = ei + NE;

  char* ws = (char*)d_ws;
  const size_t KB = (size_t)NBUCK * CAP * 4;          // 12.81 MB
  const size_t HB16 = (size_t)NN * 32 * 2;            // 6.4 MB
  unsigned int* keys   = (unsigned int*)(ws);                    // 12.81 MB
  int*          ecol   = (int*)(ws + KB);                        // 12.81 MB
  __half*       h16b   = (__half*)(ws + 2 * KB);                 // 6.4 MB
  __half*       u      = (__half*)(ws + 2 * KB + HB16);          // 6.4 MB
  __half*       v      = (__half*)(ws + 2 * KB + 2 * HB16);      // 6.4 MB
  int2*         rowseg = (int2*)(ws + 2 * KB + 3 * HB16);        // 800 KB
  int*          cursor = (int*)(ws + 2 * KB + 3 * HB16 + 800000);// NBUCK ints

  hipMemsetAsync(cursor, 0, NBUCK * 4, stream);
  k_partition1<<<NBLK_A, 512, 0, stream>>>(row, col, cursor, keys);
  k_passB_l1<<<NBUCK, 512, 0, stream>>>(cursor, keys, nf, Win, bin,
                                        Wupd, bupd, ecol, rowseg, h16b);
  k_agg_update2_uv<<<(NN + 63) / 64, 256, 0, stream>>>(rowseg, ecol, h16b,
                                                       Wupd + 2048, bupd + 32,
                                                       We1, be1, u, v);
  k_flux<<<(NE * 4 + 255) / 256, 256, 0, stream>>>(row, col, u, v, We2, be2, out);
}

// Round 14
// 205.749 us; speedup vs baseline: 1.0503x; 1.0503x over previous
//
#include <hip/hip_runtime.h>
#include <hip/hip_fp16.h>

#define NN 100000
#define NE 2500000
#define RANGE 256
#define RSHIFT 8
#define RMASK 255
#define NBUCK 391                       // ceil(NN/256)
#define CAP 8192                        // fixed bucket capacity (mean 6394, sd ~80)
#define CHUNK 8192
#define NBLK_A ((NE + CHUNK - 1) / CHUNK)   // 306
#define BCAP 8192                       // passB LDS stage cap

__device__ __forceinline__ float relu_(float x){ return fmaxf(x, 0.f); }

// ---- single-pass partition: per-block LDS histogram -> atomic bucket
//      reservation -> write packed keys (col<<8)|(row&255) into fixed-cap buckets
__global__ __launch_bounds__(512) void k_partition1(
    const int* __restrict__ row, const int* __restrict__ col,
    int* __restrict__ cursor, unsigned int* __restrict__ keys)
{
  __shared__ int hist[NBUCK];
  __shared__ int base[NBUCK];
  int t = threadIdx.x, b = blockIdx.x;
  for (int i = t; i < NBUCK; i += 512) hist[i] = 0;
  __syncthreads();
  int e0 = b * CHUNK + t;
#pragma unroll
  for (int k = 0; k < CHUNK / 512; ++k) {
    int e = e0 + k * 512;
    if (e < NE) atomicAdd(&hist[row[e] >> RSHIFT], 1);
  }
  __syncthreads();
  for (int i = t; i < NBUCK; i += 512) {
    int c = hist[i];
    base[i] = c ? (i * CAP + atomicAdd(&cursor[i], c)) : 0;
    hist[i] = 0;
  }
  __syncthreads();
#pragma unroll
  for (int k = 0; k < CHUNK / 512; ++k) {
    int e = e0 + k * 512;
    if (e < NE) {
      int r = row[e];
      int bi = r >> RSHIFT;
      int idx = atomicAdd(&hist[bi], 1);
      keys[base[bi] + idx] = ((unsigned)col[e] << RSHIFT) | (unsigned)(r & RMASK);
    }
  }
}

// per-bucket: LDS-staged keys -> hist -> scan -> rowseg + ecol placement,
// then FUSED layer-1 agg (nf recompute) + layer-1 update GEMM -> h16b direct.
__global__ __launch_bounds__(512) void k_passB_l1(
    const int* __restrict__ cursor, const unsigned int* __restrict__ keys,
    const float* __restrict__ nf, const float* __restrict__ Win,
    const float* __restrict__ bin, const float* __restrict__ W,
    const float* __restrict__ bupd,
    int* __restrict__ ecol, int2* __restrict__ rowseg,
    __half* __restrict__ h16b)
{
  __shared__ unsigned keysl[BCAP];
  __shared__ int hist[RANGE];
  __shared__ int sc[RANGE];
  __shared__ int segs[RANGE];
  __shared__ int sege[RANGE];
  __shared__ float Ws[2048];
  __shared__ float bs[32];
  int t = threadIdx.x, b = blockIdx.x;
  for (int i = t; i < 2048; i += 512) Ws[i] = W[i];
  if (t < 32) bs[t] = bupd[t];
  int s0 = b * CAP;
  int cnt = cursor[b];
  if (t < RANGE) hist[t] = 0;
  __syncthreads();
  for (int i = t; i < cnt; i += 512) {
    unsigned k = keys[s0 + i];
    if (i < BCAP) keysl[i] = k;
    atomicAdd(&hist[k & RMASK], 1);
  }
  __syncthreads();
  int my = (t < RANGE) ? hist[t] : 0;
  if (t < RANGE) sc[t] = my;
  __syncthreads();
  for (int off = 1; off < RANGE; off <<= 1) {
    int v = 0;
    if (t < RANGE && t >= off) v = sc[t - off];
    __syncthreads();
    if (t < RANGE) sc[t] += v;
    __syncthreads();
  }
  if (t < RANGE) {
    int ex = sc[t] - my;
    int n = b * RANGE + t;
    if (n < NN) rowseg[n] = make_int2(s0 + ex, s0 + sc[t]);
    segs[t] = ex;
    sege[t] = sc[t];
    hist[t] = ex;                 // placement cursor
  }
  __syncthreads();
  for (int i = t; i < cnt; i += 512) {
    unsigned key = (i < BCAP) ? keysl[i] : keys[s0 + i];
    int rl = (int)(key & RMASK);
    int idx = atomicAdd(&hist[rl], 1);
    ecol[s0 + idx] = (int)(key >> RSHIFT);
  }
  __syncthreads();   // ecol visible block-wide; segments in segs/sege

  const float2* nf2 = (const float2*)nf;
  for (int slot = t; slot < RANGE * 4; slot += 512) {
    int node = slot >> 2, q = slot & 3;
    int n = b * RANGE + node;
    if (n >= NN) continue;       // whole 4-lane group shares n
    float w0[8], w1[8], bb[8];
#pragma unroll
    for (int j = 0; j < 8; ++j) {
      w0[j] = Win[q * 8 + j];
      w1[j] = Win[32 + q * 8 + j];
      bb[j] = bin[q * 8 + j];
    }
    int ss = segs[node], ee = sege[node];
    float acc[8];
#pragma unroll
    for (int j = 0; j < 8; ++j) acc[j] = 0.f;
    int i = ss;
    for (; i + 2 <= ee; i += 2) {
      int c0 = ecol[s0 + i], c1 = ecol[s0 + i + 1];   // L2-hot
      float2 f0 = nf2[c0];
      float2 f1 = nf2[c1];
#pragma unroll
      for (int j = 0; j < 8; ++j) {
        acc[j] += relu_(fmaf(f0.x, w0[j], fmaf(f0.y, w1[j], bb[j])));
        acc[j] += relu_(fmaf(f1.x, w0[j], fmaf(f1.y, w1[j], bb[j])));
      }
    }
    if (i < ee) {
      float2 f = nf2[ecol[s0 + i]];
#pragma unroll
      for (int j = 0; j < 8; ++j)
        acc[j] += relu_(fmaf(f.x, w0[j], fmaf(f.y, w1[j], bb[j])));
    }
    float dinv = 1.0f / fmaxf((float)(ee - ss), 1.0f);
    float g[8], a[8];
    float2 fn = nf2[n];
#pragma unroll
    for (int j = 0; j < 8; ++j) {
      g[j] = acc[j] * dinv;
      a[j] = relu_(fmaf(fn.x, w0[j], fmaf(fn.y, w1[j], bb[j])));
    }
    // 64x32 GEMM slice via 4-lane shfl exchange
    float o[8];
#pragma unroll
    for (int j = 0; j < 8; ++j) o[j] = bs[q * 8 + j];
#pragma unroll
    for (int src = 0; src < 4; ++src) {
#pragma unroll
      for (int k = 0; k < 8; ++k) {
        float xh = __shfl(a[k], src, 4);
        float xg = __shfl(g[k], src, 4);
        const float* wr1 = Ws + (src * 8 + k) * 32 + q * 8;
        const float* wr2 = Ws + (32 + src * 8 + k) * 32 + q * 8;
#pragma unroll
        for (int j = 0; j < 8; ++j) {
          o[j] = fmaf(xh, wr1[j], o[j]);
          o[j] = fmaf(xg, wr2[j], o[j]);
        }
      }
    }
    uint4 pk;
    __half2* pp = (__half2*)&pk;
#pragma unroll
    for (int k = 0; k < 4; ++k)
      pp[k] = __floats2half2_rn(relu_(o[2*k]), relu_(o[2*k+1]));
    ((uint4*)h16b)[(size_t)n * 4 + q] = pk;
  }
}

// ---- fused layer-2, register-exchange version (full occupancy):
// agg = mean gather(h16b[ecol]); h2 = relu([h16b,agg]@W+b);
// u = h2@We1[0:32]+be1 ; v = h2@We1[32:64]   (64 nodes x 4 lanes / block)
__global__ __launch_bounds__(256) void k_agg_update2_uv(
    const int2* __restrict__ rowseg, const int* __restrict__ ecol,
    const __half* __restrict__ h16in, const float* __restrict__ W,
    const float* __restrict__ b, const float* __restrict__ We1,
    const float* __restrict__ be1, __half* __restrict__ u,
    __half* __restrict__ v)
{
  __shared__ float Ws[2048];
  __shared__ float Es[2048];
  __shared__ float bs[32];
  __shared__ float bes[32];
  int t = threadIdx.x;
  for (int i = t; i < 2048; i += 256) { Ws[i] = W[i]; Es[i] = We1[i]; }
  if (t < 32) { bs[t] = b[t]; bes[t] = be1[t]; }
  __syncthreads();
  int q = t & 3, ln = t >> 2;
  int n = blockIdx.x * 64 + ln;
  if (n >= NN) return;          // group-uniform exit; shfl stays intra-group
  const uint4* hv = (const uint4*)h16in;

  int2 seg = rowseg[n];
  float acc[8];
#pragma unroll
  for (int j = 0; j < 8; ++j) acc[j] = 0.f;
  int i = seg.x;
  for (; i + 2 <= seg.y; i += 2) {
    int c0 = ecol[i], c1 = ecol[i + 1];
    uint4 x0 = hv[c0 * 4 + q];
    uint4 x1 = hv[c1 * 4 + q];
    const __half2* p0 = (const __half2*)&x0;
    const __half2* p1 = (const __half2*)&x1;
#pragma unroll
    for (int k = 0; k < 4; ++k) {
      float2 f0 = __half22float2(p0[k]);
      float2 f1 = __half22float2(p1[k]);
      acc[2*k]   += f0.x + f1.x;
      acc[2*k+1] += f0.y + f1.y;
    }
  }
  if (i < seg.y) {
    uint4 x = hv[ecol[i] * 4 + q];
    const __half2* hp = (const __half2*)&x;
#pragma unroll
    for (int k = 0; k < 4; ++k) {
      float2 f = __half22float2(hp[k]);
      acc[2*k] += f.x; acc[2*k+1] += f.y;
    }
  }
  float dinv = 1.0f / fmaxf((float)(seg.y - seg.x), 1.0f);
  float a[8], g[8];
  {
    uint4 hx = hv[n * 4 + q];
    const __half2* hp = (const __half2*)&hx;
#pragma unroll
    for (int k = 0; k < 4; ++k) {
      float2 f = __half22float2(hp[k]);
      a[2*k] = f.x; a[2*k+1] = f.y;
      g[2*k] = acc[2*k] * dinv; g[2*k+1] = acc[2*k+1] * dinv;
    }
  }
  // GEMM1: h2 = relu([a|g] @ W + b), 4-lane shfl exchange
  float h2[8];
#pragma unroll
  for (int j = 0; j < 8; ++j) h2[j] = bs[q*8 + j];
#pragma unroll
  for (int src = 0; src < 4; ++src) {
#pragma unroll
    for (int k = 0; k < 8; ++k) {
      float xh = __shfl(a[k], src, 4);
      float xg = __shfl(g[k], src, 4);
      const float* wr1 = Ws + (src * 8 + k) * 32 + q * 8;
      const float* wr2 = Ws + (32 + src * 8 + k) * 32 + q * 8;
#pragma unroll
      for (int j = 0; j < 8; ++j) {
        h2[j] = fmaf(xh, wr1[j], h2[j]);
        h2[j] = fmaf(xg, wr2[j], h2[j]);
      }
    }
  }
#pragma unroll
  for (int j = 0; j < 8; ++j) h2[j] = relu_(h2[j]);
  // GEMM2: u = h2@Es[0:32]+be1 ; v = h2@Es[32:64]
  float au[8], av[8];
#pragma unroll
  for (int j = 0; j < 8; ++j) { au[j] = bes[q*8 + j]; av[j] = 0.f; }
#pragma unroll
  for (int src = 0; src < 4; ++src) {
#pragma unroll
    for (int k = 0; k < 8; ++k) {
      float xk = __shfl(h2[k], src, 4);
      const float* wu = Es + (src * 8 + k) * 32 + q * 8;
      const float* wv = Es + (32 + src * 8 + k) * 32 + q * 8;
#pragma unroll
      for (int j = 0; j < 8; ++j) {
        au[j] = fmaf(xk, wu[j], au[j]);
        av[j] = fmaf(xk, wv[j], av[j]);
      }
    }
  }
  uint4 pu, pv;
  __half2* up = (__half2*)&pu;
  __half2* vp = (__half2*)&pv;
#pragma unroll
  for (int k = 0; k < 4; ++k) {
    up[k] = __floats2half2_rn(au[2*k], au[2*k+1]);
    vp[k] = __floats2half2_rn(av[2*k], av[2*k+1]);
  }
  ((uint4*)u)[n * 4 + q] = pu;
  ((uint4*)v)[n * 4 + q] = pv;
}

// flux[e] = relu(u[row]+v[col]).We2 + be2   (4 lanes/edge, uint4 fp16 loads)
__global__ __launch_bounds__(256) void k_flux(
    const int* __restrict__ row, const int* __restrict__ col,
    const __half* __restrict__ u, const __half* __restrict__ v,
    const float* __restrict__ We2, const float* __restrict__ be2,
    float* __restrict__ out)
{
  int gid = blockIdx.x * 256 + threadIdx.x;
  int e = gid >> 2, q = gid & 3;
  if (e >= NE) return;
  int r = row[e], c = col[e];
  uint4 ua = ((const uint4*)u)[r * 4 + q];   // 8 halfs
  uint4 vb = ((const uint4*)v)[c * 4 + q];
  const __half2* ah = (const __half2*)&ua;
  const __half2* bh = (const __half2*)&vb;
  const float4* w4 = (const float4*)(We2 + q * 8);
  float4 w0 = w4[0], w1 = w4[1];
  float p = 0.f;
  {
    float2 a = __half22float2(ah[0]), b = __half22float2(bh[0]);
    p += relu_(a.x + b.x) * w0.x + relu_(a.y + b.y) * w0.y;
    a = __half22float2(ah[1]); b = __half22float2(bh[1]);
    p += relu_(a.x + b.x) * w0.z + relu_(a.y + b.y) * w0.w;
    a = __half22float2(ah[2]); b = __half22float2(bh[2]);
    p += relu_(a.x + b.x) * w1.x + relu_(a.y + b.y) * w1.y;
    a = __half22float2(ah[3]); b = __half22float2(bh[3]);
    p += relu_(a.x + b.x) * w1.z + relu_(a.y + b.y) * w1.w;
  }
  p += __shfl_xor(p, 1, 4);
  p += __shfl_xor(p, 2, 4);
  if (q == 0) out[e] = p + be2[0];
}

extern "C" void kernel_launch(void* const* d_in, const int* in_sizes, int n_in,
                              void* d_out, int out_size, void* d_ws, size_t ws_size,
                              hipStream_t stream) {
  const float* nf   = (const float*)d_in[0];
  const int*   ei   = (const int*)d_in[1];
  const float* Win  = (const float*)d_in[2];
  const float* bin  = (const float*)d_in[3];
  const float* Wupd = (const float*)d_in[4];
  const float* bupd = (const float*)d_in[5];
  const float* We1  = (const float*)d_in[6];
  const float* be1  = (const float*)d_in[7];
  const float* We2  = (const float*)d_in[8];
  const float* be2  = (const float*)d_in[9];
  float* out = (float*)d_out;

  const int* row = ei;
  const int* col = ei + NE;

  char* ws = (char*)d_ws;
  const size_t KB = (size_t)NBUCK * CAP * 4;          // 12.81 MB
  const size_t HB16 = (size_t)NN * 32 * 2;            // 6.4 MB
  unsigned int* keys   = (unsigned int*)(ws);                    // 12.81 MB
  int*          ecol   = (int*)(ws + KB);                        // 12.81 MB
  __half*       h16b   = (__half*)(ws + 2 * KB);                 // 6.4 MB
  __half*       u      = (__half*)(ws + 2 * KB + HB16);          // 6.4 MB
  __half*       v      = (__half*)(ws + 2 * KB + 2 * HB16);      // 6.4 MB
  int2*         rowseg = (int2*)(ws + 2 * KB + 3 * HB16);        // 800 KB
  int*          cursor = (int*)(ws + 2 * KB + 3 * HB16 + 800000);// NBUCK ints

  hipMemsetAsync(cursor, 0, NBUCK * 4, stream);
  k_partition1<<<NBLK_A, 512, 0, stream>>>(row, col, cursor, keys);
  k_passB_l1<<<NBUCK, 512, 0, stream>>>(cursor, keys, nf, Win, bin,
                                        Wupd, bupd, ecol, rowseg, h16b);
  k_agg_update2_uv<<<(NN + 63) / 64, 256, 0, stream>>>(rowseg, ecol, h16b,
                                                       Wupd + 2048, bupd + 32,
                                                       We1, be1, u, v);
  k_flux<<<(NE * 4 + 255) / 256, 256, 0, stream>>>(row, col, u, v, We2, be2, out);
}